// Round 13
// baseline (647.072 us; speedup 1.0000x reference)
//
#include <hip/hip_runtime.h>
#include <hip/hip_bf16.h>

#define N_NODES 50000
#define N_EDGES 800000
#define N_FEAT 128
#define HIDDEN 256
#define N_GRAPHS 256
#define N_CLASSES 10

#define NBUCK ((N_NODES + 255) / 256)      // 196 dst-buckets of 256 nodes
#define EPB 2048                           // edges per scatter block
#define NBLK_S ((N_EDGES + EPB - 1) / EPB) // 391

typedef __hip_bfloat16 bf16_t;
typedef short bf16x8 __attribute__((ext_vector_type(8)));
typedef float f32x4 __attribute__((ext_vector_type(4)));

__device__ inline float bfb2f(short s) {
    unsigned u = ((unsigned)(unsigned short)s) << 16;
    float f; __builtin_memcpy(&f, &u, 4); return f;
}
__device__ inline short f2bfb(float f) {
    bf16_t b = __float2bfloat16(f);
    short s; __builtin_memcpy(&s, &b, 2); return s;
}

// ---------------- CSR build: two-level bucket sort, parallel scans ----------------

__global__ __launch_bounds__(256) void bucket_hist_kernel(const int* __restrict__ ei,
                                                          unsigned* __restrict__ histT) {
    __shared__ unsigned lh[NBUCK];
    int t = threadIdx.x, j = blockIdx.x;
    for (int i = t; i < NBUCK; i += 256) lh[i] = 0;
    __syncthreads();
    int base = j * EPB;
    #pragma unroll
    for (int it = 0; it < EPB / 256; it++) {
        int e = base + it * 256 + t;
        if (e < N_EDGES) atomicAdd(&lh[(unsigned)ei[N_EDGES + e] >> 8], 1u);
    }
    __syncthreads();
    for (int i = t; i < NBUCK; i += 256) histT[(size_t)i * NBLK_S + j] = lh[i];
}

__global__ __launch_bounds__(256) void bucket_scan_a_kernel(unsigned* __restrict__ histT,
                                                            unsigned* __restrict__ bucketTot) {
    __shared__ unsigned tmp[256];
    int b = blockIdx.x, t = threadIdx.x;
    unsigned* row = histT + (size_t)b * NBLK_S;
    int i0 = t * 2, i1 = t * 2 + 1;
    unsigned v0 = (i0 < NBLK_S) ? row[i0] : 0u;
    unsigned v1 = (i1 < NBLK_S) ? row[i1] : 0u;
    unsigned s = v0 + v1;
    tmp[t] = s;
    __syncthreads();
    #pragma unroll
    for (int off = 1; off < 256; off <<= 1) {
        unsigned a = (t >= off) ? tmp[t - off] : 0u;
        __syncthreads();
        tmp[t] += a;
        __syncthreads();
    }
    unsigned base = tmp[t] - s;
    if (i0 < NBLK_S) row[i0] = base;
    if (i1 < NBLK_S) row[i1] = base + v0;
    if (t == 255) bucketTot[b] = tmp[255];
}

__global__ __launch_bounds__(256) void bucket_scan_b_kernel(const unsigned* __restrict__ bucketTot,
                                                            unsigned* __restrict__ bucketBase) {
    __shared__ unsigned tmp[256];
    int t = threadIdx.x;
    unsigned v = (t < NBUCK) ? bucketTot[t] : 0u;
    tmp[t] = v;
    __syncthreads();
    #pragma unroll
    for (int off = 1; off < 256; off <<= 1) {
        unsigned a = (t >= off) ? tmp[t - off] : 0u;
        __syncthreads();
        tmp[t] += a;
        __syncthreads();
    }
    if (t < NBUCK) bucketBase[t] = tmp[t] - v;
    if (t == NBUCK - 1) bucketBase[NBUCK] = tmp[t];
}

__global__ __launch_bounds__(256) void bucket_scatter_kernel(const int* __restrict__ ei,
                                                             const unsigned* __restrict__ histT,
                                                             const unsigned* __restrict__ bucketBase,
                                                             unsigned long long* __restrict__ ebuf) {
    __shared__ unsigned lcur[NBUCK];
    int t = threadIdx.x, j = blockIdx.x;
    for (int i = t; i < NBUCK; i += 256)
        lcur[i] = histT[(size_t)i * NBLK_S + j] + bucketBase[i];
    __syncthreads();
    int base = j * EPB;
    #pragma unroll
    for (int it = 0; it < EPB / 256; it++) {
        int e = base + it * 256 + t;
        if (e < N_EDGES) {
            unsigned src = (unsigned)ei[e];
            unsigned dst = (unsigned)ei[N_EDGES + e];
            unsigned pos = atomicAdd(&lcur[dst >> 8], 1u);
            ebuf[pos] = (unsigned long long)src | ((unsigned long long)dst << 32);
        }
    }
}

__global__ __launch_bounds__(256) void fine_fill_kernel(const unsigned long long* __restrict__ ebuf,
                                                        const unsigned* __restrict__ bucketBase,
                                                        unsigned* __restrict__ rowptr,
                                                        int* __restrict__ adj) {
    __shared__ unsigned ldeg[256], lcur[256], tmp[256];
    int b = blockIdx.x, t = threadIdx.x;
    unsigned sbase = bucketBase[b];
    int scnt = (int)(bucketBase[b + 1] - sbase);
    ldeg[t] = 0;
    __syncthreads();
    for (int k = t; k < scnt; k += 256) {
        unsigned dst = (unsigned)(ebuf[sbase + k] >> 32);
        atomicAdd(&ldeg[dst & 255], 1u);
    }
    __syncthreads();
    unsigned v = ldeg[t];
    tmp[t] = v;
    __syncthreads();
    for (int off = 1; off < 256; off <<= 1) {
        unsigned a = (t >= off) ? tmp[t - off] : 0u;
        __syncthreads();
        tmp[t] += a;
        __syncthreads();
    }
    unsigned exc = tmp[t] - v;
    lcur[t] = exc;
    int gnode = b * 256 + t;
    if (gnode < N_NODES) rowptr[gnode] = sbase + exc;
    if (b == NBUCK - 1 && t == 0) rowptr[N_NODES] = N_EDGES;
    __syncthreads();
    for (int k = t; k < scnt; k += 256) {
        unsigned long long p = ebuf[sbase + k];
        unsigned dst = (unsigned)(p >> 32);
        unsigned pos = atomicAdd(&lcur[dst & 255], 1u);
        adj[sbase + pos] = (int)(p & 0xffffffffu);
    }
}

// ---------------- x fp32 -> bf16 convert ----------------

__global__ __launch_bounds__(256) void convert_x_kernel(const float* __restrict__ x,
                                                        bf16_t* __restrict__ xb) {
    int i = blockIdx.x * 256 + threadIdx.x;
    if (i < N_NODES * N_FEAT / 4) {
        float4 v = reinterpret_cast<const float4*>(x)[i];
        short4 o;
        o.x = f2bfb(v.x); o.y = f2bfb(v.y); o.z = f2bfb(v.z); o.w = f2bfb(v.w);
        reinterpret_cast<short4*>(xb)[i] = o;
    }
}

// ---------------- Weight prep: fp32 W[K][256] -> bf16 Wt[256][K] ----------------

__global__ __launch_bounds__(256) void prep_weights_kernel(
    const float* __restrict__ c1_w0, const float* __restrict__ c1_w1,
    const float* __restrict__ cs_w0, const float* __restrict__ cs_w1,
    bf16_t* __restrict__ wt)
{
    __shared__ float T[32][33];
    int z = blockIdx.z;
    const float* src; int K; size_t off;
    if (z == 0)      { src = c1_w0; K = N_FEAT;  off = 0; }
    else if (z == 1) { src = c1_w1; K = HIDDEN;  off = 32768; }
    else {
        int i = (z - 2) >> 1;
        src = (((z - 2) & 1) ? cs_w1 : cs_w0) + (size_t)i * HIDDEN * HIDDEN;
        K = HIDDEN;
        off = 32768 + (size_t)(z - 1) * 65536;
    }
    int k0 = blockIdx.x * 32, n0 = blockIdx.y * 32;
    if (k0 >= K) return;
    int t = threadIdx.x;
    int r = t >> 3, c4 = (t & 7) * 4;
    float4 v = *reinterpret_cast<const float4*>(src + (size_t)(k0 + r) * HIDDEN + n0 + c4);
    T[r][c4 + 0] = v.x; T[r][c4 + 1] = v.y; T[r][c4 + 2] = v.z; T[r][c4 + 3] = v.w;
    __syncthreads();
    int n = t >> 3, kc = (t & 7) * 4;
    short4 o;
    o.x = f2bfb(T[kc + 0][n]); o.y = f2bfb(T[kc + 1][n]);
    o.z = f2bfb(T[kc + 2][n]); o.w = f2bfb(T[kc + 3][n]);
    *reinterpret_cast<short4*>((short*)wt + off + (size_t)(n0 + n) * K + k0 + kc) = o;
}

// ---------------- Fused GIN layer: gather+aggregate -> MLP -> BN ----------------
// One block = 128 node rows x full 256 output cols. 512 threads, 8 waves (2x4),
// GEMM wave tile 64x64. LDS 64KB overlay: gathered A [128][K0] / H1 [128][256] / C-stage.
// Phase 0 gathers neighbor sums straight into LDS (no global intermediate).
// Swizzle on 16B chunks: short-index col ^ ((row&7)<<3).

template<int K0>
__global__ __launch_bounds__(512) void gin_layer_kernel(
    const bf16_t* __restrict__ X, const int* __restrict__ adj,
    const unsigned* __restrict__ rowptr, const float* __restrict__ eps_arr, int eps_idx,
    const bf16_t* __restrict__ W0t, const float* __restrict__ b0,
    const bf16_t* __restrict__ W1t, const float* __restrict__ b1,
    const float* __restrict__ bn_g, const float* __restrict__ bn_b,
    const float* __restrict__ bn_m, const float* __restrict__ bn_v,
    bf16_t* __restrict__ C, int M)
{
    __shared__ short sh[32768];   // 64 KB
    int tid = threadIdx.x, lane = tid & 63, wave = tid >> 6;
    int wr = wave >> 2, wc = wave & 3;
    int row0 = blockIdx.x * 128;
    int fr = lane & 15, fk = (lane >> 4) * 8;
    float ep = 1.f + eps_arr[eps_idx];

    const short* xs = (const short*)X;
    const short* W0b = (const short*)W0t;
    const short* W1b = (const short*)W1t;

    // ---- Phase 0: gather + aggregate 16 rows per wave directly into LDS ----
    if (K0 == 256) {
        int half = lane >> 5, l5 = lane & 31;          // 32 lanes x 16B = full 512B row
        for (int rr = 0; rr < 16; rr++) {
            int r = wave * 16 + rr;
            int n = row0 + r;
            unsigned e = 0, end = 0;
            if (n < M) { e = rowptr[n]; end = rowptr[n + 1]; }
            float acc[8] = {};
            for (; e + 8 <= end; e += 8) {
                int s0 = adj[e + half];
                int s1 = adj[e + 2 + half];
                int s2 = adj[e + 4 + half];
                int s3 = adj[e + 6 + half];
                bf16x8 v0 = *reinterpret_cast<const bf16x8*>(xs + (unsigned)s0 * 256 + l5 * 8);
                bf16x8 v1 = *reinterpret_cast<const bf16x8*>(xs + (unsigned)s1 * 256 + l5 * 8);
                bf16x8 v2 = *reinterpret_cast<const bf16x8*>(xs + (unsigned)s2 * 256 + l5 * 8);
                bf16x8 v3 = *reinterpret_cast<const bf16x8*>(xs + (unsigned)s3 * 256 + l5 * 8);
                #pragma unroll
                for (int j = 0; j < 8; j++)
                    acc[j] += (bfb2f(v0[j]) + bfb2f(v1[j])) + (bfb2f(v2[j]) + bfb2f(v3[j]));
            }
            for (; e + 2 <= end; e += 2) {
                int s0 = adj[e + half];
                bf16x8 v0 = *reinterpret_cast<const bf16x8*>(xs + (unsigned)s0 * 256 + l5 * 8);
                #pragma unroll
                for (int j = 0; j < 8; j++) acc[j] += bfb2f(v0[j]);
            }
            if (e < end && half == 0) {
                bf16x8 v0 = *reinterpret_cast<const bf16x8*>(xs + (unsigned)adj[e] * 256 + l5 * 8);
                #pragma unroll
                for (int j = 0; j < 8; j++) acc[j] += bfb2f(v0[j]);
            }
            if (n < M && half == 0) {
                bf16x8 sv = *reinterpret_cast<const bf16x8*>(xs + (unsigned)n * 256 + l5 * 8);
                #pragma unroll
                for (int j = 0; j < 8; j++) acc[j] += ep * bfb2f(sv[j]);
            }
            #pragma unroll
            for (int j = 0; j < 8; j++) acc[j] += __shfl_xor(acc[j], 32);
            if (half == 0) {
                bf16x8 o;
                #pragma unroll
                for (int j = 0; j < 8; j++) o[j] = f2bfb(acc[j]);
                *reinterpret_cast<bf16x8*>(&sh[r * 256 + ((l5 * 8) ^ ((r & 7) << 3))]) = o;
            }
        }
    } else {   // K0 == 128
        int q = lane >> 4, l4 = lane & 15;             // quarter-wave per edge, 4 in flight
        for (int rr = 0; rr < 16; rr++) {
            int r = wave * 16 + rr;
            int n = row0 + r;
            unsigned e = 0, end = 0;
            if (n < M) { e = rowptr[n]; end = rowptr[n + 1]; }
            float acc[8] = {};
            for (; e + 8 <= end; e += 8) {
                int s0 = adj[e + q];
                int s1 = adj[e + 4 + q];
                bf16x8 v0 = *reinterpret_cast<const bf16x8*>(xs + (unsigned)s0 * 128 + l4 * 8);
                bf16x8 v1 = *reinterpret_cast<const bf16x8*>(xs + (unsigned)s1 * 128 + l4 * 8);
                #pragma unroll
                for (int j = 0; j < 8; j++) acc[j] += bfb2f(v0[j]) + bfb2f(v1[j]);
            }
            for (; e + 4 <= end; e += 4) {
                int s0 = adj[e + q];
                bf16x8 v0 = *reinterpret_cast<const bf16x8*>(xs + (unsigned)s0 * 128 + l4 * 8);
                #pragma unroll
                for (int j = 0; j < 8; j++) acc[j] += bfb2f(v0[j]);
            }
            int rem = (int)(end - e);
            if (q < rem) {
                bf16x8 v0 = *reinterpret_cast<const bf16x8*>(xs + (unsigned)adj[e + q] * 128 + l4 * 8);
                #pragma unroll
                for (int j = 0; j < 8; j++) acc[j] += bfb2f(v0[j]);
            }
            if (n < M && q == 0) {
                bf16x8 sv = *reinterpret_cast<const bf16x8*>(xs + (unsigned)n * 128 + l4 * 8);
                #pragma unroll
                for (int j = 0; j < 8; j++) acc[j] += ep * bfb2f(sv[j]);
            }
            #pragma unroll
            for (int j = 0; j < 8; j++) {
                acc[j] += __shfl_xor(acc[j], 16);
                acc[j] += __shfl_xor(acc[j], 32);
            }
            if (lane < 16) {
                bf16x8 o;
                #pragma unroll
                for (int j = 0; j < 8; j++) o[j] = f2bfb(acc[j]);
                *reinterpret_cast<bf16x8*>(&sh[r * 128 + ((l4 * 8) ^ ((r & 7) << 3))]) = o;
            }
        }
    }
    __syncthreads();

    // ---- Phase 1: GEMM0, acc = A @ W0 ----
    f32x4 acc[4][4] = {};
    #pragma unroll
    for (int ks = 0; ks < K0 / 32; ks++) {
        bf16x8 a[4], b[4];
        #pragma unroll
        for (int m = 0; m < 4; m++) {
            int r = wr * 64 + m * 16 + fr;
            a[m] = *reinterpret_cast<const bf16x8*>(&sh[r * K0 + ((ks * 32 + fk) ^ ((r & 7) << 3))]);
        }
        #pragma unroll
        for (int n = 0; n < 4; n++)
            b[n] = *reinterpret_cast<const bf16x8*>(W0b + (size_t)(wc * 64 + n * 16 + fr) * K0 + ks * 32 + fk);
        #pragma unroll
        for (int m = 0; m < 4; m++)
            #pragma unroll
            for (int n = 0; n < 4; n++)
                acc[m][n] = __builtin_amdgcn_mfma_f32_16x16x32_bf16(a[m], b[n], acc[m][n], 0, 0, 0);
    }
    __syncthreads();

    // ---- Phase 2: H1 = relu(acc + b0) -> same LDS, [128][256] swizzled ----
    #pragma unroll
    for (int m = 0; m < 4; m++) {
        int rl = wr * 64 + m * 16 + (lane >> 4) * 4;
        #pragma unroll
        for (int n = 0; n < 4; n++) {
            int cl = wc * 64 + n * 16 + fr;
            float bi = b0[cl];
            #pragma unroll
            for (int r = 0; r < 4; r++) {
                int rr = rl + r;
                sh[rr * 256 + (cl ^ ((rr & 7) << 3))] = f2bfb(fmaxf(acc[m][n][r] + bi, 0.f));
            }
        }
    }
    __syncthreads();

    // ---- Phase 3: GEMM1, acc1 = H1 @ W1 (K = 256) ----
    f32x4 acc1[4][4] = {};
    #pragma unroll
    for (int ks = 0; ks < 8; ks++) {
        bf16x8 a[4], b[4];
        #pragma unroll
        for (int m = 0; m < 4; m++) {
            int r = wr * 64 + m * 16 + fr;
            a[m] = *reinterpret_cast<const bf16x8*>(&sh[r * 256 + ((ks * 32 + fk) ^ ((r & 7) << 3))]);
        }
        #pragma unroll
        for (int n = 0; n < 4; n++)
            b[n] = *reinterpret_cast<const bf16x8*>(W1b + (size_t)(wc * 64 + n * 16 + fr) * 256 + ks * 32 + fk);
        #pragma unroll
        for (int m = 0; m < 4; m++)
            #pragma unroll
            for (int n = 0; n < 4; n++)
                acc1[m][n] = __builtin_amdgcn_mfma_f32_16x16x32_bf16(a[m], b[n], acc1[m][n], 0, 0, 0);
    }
    __syncthreads();

    // ---- Phase 4: epilogue BN(relu(acc1+b1)) -> LDS -> coalesced store ----
    #pragma unroll
    for (int m = 0; m < 4; m++) {
        int rl = wr * 64 + m * 16 + (lane >> 4) * 4;
        #pragma unroll
        for (int n = 0; n < 4; n++) {
            int cl = wc * 64 + n * 16 + fr;
            float bi = b1[cl];
            float bnm = bn_m[cl], bns = rsqrtf(bn_v[cl] + 1e-5f), bng = bn_g[cl], bnb = bn_b[cl];
            #pragma unroll
            for (int r = 0; r < 4; r++) {
                int rr = rl + r;
                float v = fmaxf(acc1[m][n][r] + bi, 0.f);
                v = (v - bnm) * bns * bng + bnb;
                sh[rr * 256 + (cl ^ ((rr & 7) << 3))] = f2bfb(v);
            }
        }
    }
    __syncthreads();
    #pragma unroll
    for (int it = 0; it < 8; it++) {
        int c = it * 512 + tid;
        int r = c >> 5, col = (c & 31) * 8;
        int gr = row0 + r;
        if (gr < M) {
            bf16x8 v = *reinterpret_cast<const bf16x8*>(&sh[r * 256 + (col ^ ((r & 7) << 3))]);
            *reinterpret_cast<bf16x8*>((short*)C + (size_t)gr * 256 + col) = v;
        }
    }
}

// ---------------- Pool ----------------

__global__ __launch_bounds__(256) void pool_kernel(const bf16_t* __restrict__ h,
                                                   const int* __restrict__ batch,
                                                   float* __restrict__ pooled) {
    __shared__ int sbs[2];
    __shared__ float red[4][HIDDEN];
    int g = blockIdx.x;
    if (threadIdx.x == 0) {
        int lo = 0, hi = N_NODES;
        while (lo < hi) { int mid = (lo + hi) >> 1; if (batch[mid] < g) lo = mid + 1; else hi = mid; }
        sbs[0] = lo;
        hi = N_NODES;
        while (lo < hi) { int mid = (lo + hi) >> 1; if (batch[mid] < g + 1) lo = mid + 1; else hi = mid; }
        sbs[1] = lo;
    }
    __syncthreads();
    int sbeg = sbs[0], send = sbs[1];
    int w = threadIdx.x >> 6, lane = threadIdx.x & 63;
    int half = lane >> 5, l5 = lane & 31;
    const short* hb = (const short*)h;
    float acc[8] = {};
    for (int n = sbeg + w * 2 + half; n < send; n += 8) {
        bf16x8 v = *reinterpret_cast<const bf16x8*>(hb + (size_t)n * HIDDEN + l5 * 8);
        #pragma unroll
        for (int j = 0; j < 8; j++) acc[j] += bfb2f(v[j]);
    }
    #pragma unroll
    for (int j = 0; j < 8; j++) acc[j] += __shfl_xor(acc[j], 32);
    if (half == 0) {
        #pragma unroll
        for (int j = 0; j < 8; j++) red[w][l5 * 8 + j] = acc[j];
    }
    __syncthreads();
    int t = threadIdx.x;
    float s = red[0][t] + red[1][t] + red[2][t] + red[3][t];
    float cnt = (float)(send - sbeg);
    pooled[g * HIDDEN + t] = s / fmaxf(cnt, 1.f);
}

// ---------------- Head ----------------

__global__ void head_kernel(const float* __restrict__ pooled,
                            const float* __restrict__ w1, const float* __restrict__ b1,
                            const float* __restrict__ w2, const float* __restrict__ b2,
                            float* __restrict__ out) {
    int g = blockIdx.x, t = threadIdx.x;
    __shared__ float p[HIDDEN];
    __shared__ float h1[HIDDEN];
    __shared__ float lg[N_CLASSES];
    p[t] = pooled[g * HIDDEN + t];
    __syncthreads();
    float acc = b1[t];
    for (int k = 0; k < HIDDEN; k++) acc += p[k] * w1[k * HIDDEN + t];
    h1[t] = fmaxf(acc, 0.f);
    __syncthreads();
    if (t < N_CLASSES) {
        float a = b2[t];
        for (int k = 0; k < HIDDEN; k++) a += h1[k] * w2[k * N_CLASSES + t];
        lg[t] = a;
    }
    __syncthreads();
    if (t == 0) {
        float mx = lg[0];
        for (int j = 1; j < N_CLASSES; j++) mx = fmaxf(mx, lg[j]);
        float se = 0.f;
        for (int j = 0; j < N_CLASSES; j++) se += expf(lg[j] - mx);
        float lse = mx + logf(se);
        for (int j = 0; j < N_CLASSES; j++) out[g * N_CLASSES + j] = lg[j] - lse;
    }
}

// ---------------- Launch ----------------

extern "C" void kernel_launch(void* const* d_in, const int* in_sizes, int n_in,
                              void* d_out, int out_size, void* d_ws, size_t ws_size,
                              hipStream_t stream) {
    const float* x       = (const float*)d_in[0];
    const int*   ei      = (const int*)d_in[1];     // int32 on device (harness contract)
    const int*   batch   = (const int*)d_in[2];
    const float* c1_w0   = (const float*)d_in[3];
    const float* c1_b0   = (const float*)d_in[4];
    const float* c1_w1   = (const float*)d_in[5];
    const float* c1_b1   = (const float*)d_in[6];
    const float* c1_g    = (const float*)d_in[7];
    const float* c1_be   = (const float*)d_in[8];
    const float* c1_m    = (const float*)d_in[9];
    const float* c1_v    = (const float*)d_in[10];
    const float* cs_w0   = (const float*)d_in[11];
    const float* cs_b0   = (const float*)d_in[12];
    const float* cs_w1   = (const float*)d_in[13];
    const float* cs_b1   = (const float*)d_in[14];
    const float* cs_g    = (const float*)d_in[15];
    const float* cs_be   = (const float*)d_in[16];
    const float* cs_m    = (const float*)d_in[17];
    const float* cs_v    = (const float*)d_in[18];
    const float* eps     = (const float*)d_in[19];
    const float* lin1_w  = (const float*)d_in[20];
    const float* lin1_b  = (const float*)d_in[21];
    const float* lin2_w  = (const float*)d_in[22];
    const float* lin2_b  = (const float*)d_in[23];

    char* ws = (char*)d_ws;
    size_t off = 0;
    auto alloc = [&](size_t bytes) -> void* {
        void* p = ws + off;
        off += (bytes + 255) & ~(size_t)255;
        return p;
    };

    unsigned* histT      = (unsigned*)alloc((size_t)NBUCK * NBLK_S * 4);
    unsigned* bucketTot  = (unsigned*)alloc(NBUCK * 4);
    unsigned* bucketBase = (unsigned*)alloc((NBUCK + 1) * 4);
    unsigned long long* ebuf = (unsigned long long*)alloc((size_t)N_EDGES * 8);
    unsigned* rowptr     = (unsigned*)alloc((N_NODES + 1) * 4);
    int*      adj        = (int*)alloc(N_EDGES * 4);
    bf16_t*   Wt         = (bf16_t*)alloc((size_t)(32768 + 7 * 65536) * 2);
    bf16_t*   xb         = (bf16_t*)alloc((size_t)N_NODES * N_FEAT * 2);
    bf16_t*   BA         = (bf16_t*)alloc((size_t)N_NODES * HIDDEN * 2);
    bf16_t*   BB         = (bf16_t*)alloc((size_t)N_NODES * HIDDEN * 2);
    float*    pooled     = (float*)alloc(N_GRAPHS * HIDDEN * 4);

    bf16_t* wt_10 = Wt;                       // c1_w0^T  [256][128]
    bf16_t* wt_11 = Wt + 32768;               // c1_w1^T  [256][256]
    auto wt_c0 = [&](int i) { return Wt + 32768 + (size_t)(1 + 2 * i) * 65536; };
    auto wt_c1 = [&](int i) { return Wt + 32768 + (size_t)(2 + 2 * i) * 65536; };

    // CSR build (5 dispatches, all parallel)
    bucket_hist_kernel<<<NBLK_S, 256, 0, stream>>>(ei, histT);
    bucket_scan_a_kernel<<<NBUCK, 256, 0, stream>>>(histT, bucketTot);
    bucket_scan_b_kernel<<<1, 256, 0, stream>>>(bucketTot, bucketBase);
    bucket_scatter_kernel<<<NBLK_S, 256, 0, stream>>>(ei, histT, bucketBase, ebuf);
    fine_fill_kernel<<<NBUCK, 256, 0, stream>>>(ebuf, bucketBase, rowptr, adj);

    convert_x_kernel<<<(N_NODES * N_FEAT / 4 + 255) / 256, 256, 0, stream>>>(x, xb);
    prep_weights_kernel<<<dim3(8, 8, 8), 256, 0, stream>>>(c1_w0, c1_w1, cs_w0, cs_w1, Wt);

    int cgrid = (N_NODES + 127) / 128;   // 391

    // Layer 1 (F=128): fused gather+MLP, xb -> BA
    gin_layer_kernel<128><<<cgrid, 512, 0, stream>>>(xb, adj, rowptr, eps, 0,
                                                     wt_10, c1_b0, wt_11, c1_b1,
                                                     c1_g, c1_be, c1_m, c1_v, BA, N_NODES);

    // Layers 2..4 (F=256): fused, ping-pong BA <-> BB
    const bf16_t* src = BA;
    bf16_t* dst = BB;
    for (int i = 0; i < 3; i++) {
        gin_layer_kernel<256><<<cgrid, 512, 0, stream>>>(src, adj, rowptr, eps, i + 1,
                                                         wt_c0(i), cs_b0 + i * HIDDEN,
                                                         wt_c1(i), cs_b1 + i * HIDDEN,
                                                         cs_g + i * HIDDEN, cs_be + i * HIDDEN,
                                                         cs_m + i * HIDDEN, cs_v + i * HIDDEN,
                                                         dst, N_NODES);
        const bf16_t* tmp = src; src = dst; dst = (bf16_t*)tmp;
    }
    // after 3 iterations: final output is in `src` (BA -> BB -> BA -> BB): src == BB

    pool_kernel<<<N_GRAPHS, 256, 0, stream>>>(src, batch, pooled);
    head_kernel<<<N_GRAPHS, HIDDEN, 0, stream>>>(pooled, lin1_w, lin1_b, lin2_w, lin2_b, (float*)d_out);
}

// Round 14
// 440.361 us; speedup vs baseline: 1.4694x; 1.4694x over previous
//
#include <hip/hip_runtime.h>
#include <hip/hip_bf16.h>

#define N_NODES 50000
#define N_EDGES 800000
#define N_FEAT 128
#define HIDDEN 256
#define N_GRAPHS 256
#define N_CLASSES 10
#define MPAD 50176                         // padded row count for GEMM A/C buffers

#define NBUCK ((N_NODES + 255) / 256)      // 196 dst-buckets of 256 nodes
#define EPB 2048                           // edges per scatter block
#define NBLK_S ((N_EDGES + EPB - 1) / EPB) // 391

typedef __hip_bfloat16 bf16_t;
typedef short bf16x8 __attribute__((ext_vector_type(8)));
typedef float f32x4 __attribute__((ext_vector_type(4)));

typedef unsigned int u32;
typedef u32 __attribute__((address_space(1))) gu32;
typedef u32 __attribute__((address_space(3))) lu32;

__device__ inline float bfb2f(short s) {
    unsigned u = ((unsigned)(unsigned short)s) << 16;
    float f; __builtin_memcpy(&f, &u, 4); return f;
}
__device__ inline short f2bfb(float f) {
    bf16_t b = __float2bfloat16(f);
    short s; __builtin_memcpy(&s, &b, 2); return s;
}

// async 16B global -> LDS copy (gfx950 global_load_lds_dwordx4)
__device__ inline void async_copy16(const void* gsrc, void* ldst) {
    __builtin_amdgcn_global_load_lds((const gu32*)gsrc, (lu32*)ldst, 16, 0, 0);
}

// ---------------- CSR build: two-level bucket sort, parallel scans ----------------

__global__ __launch_bounds__(256) void bucket_hist_kernel(const int* __restrict__ ei,
                                                          unsigned* __restrict__ histT) {
    __shared__ unsigned lh[NBUCK];
    int t = threadIdx.x, j = blockIdx.x;
    for (int i = t; i < NBUCK; i += 256) lh[i] = 0;
    __syncthreads();
    int base = j * EPB;
    #pragma unroll
    for (int it = 0; it < EPB / 256; it++) {
        int e = base + it * 256 + t;
        if (e < N_EDGES) atomicAdd(&lh[(unsigned)ei[N_EDGES + e] >> 8], 1u);
    }
    __syncthreads();
    for (int i = t; i < NBUCK; i += 256) histT[(size_t)i * NBLK_S + j] = lh[i];
}

__global__ __launch_bounds__(256) void bucket_scan_a_kernel(unsigned* __restrict__ histT,
                                                            unsigned* __restrict__ bucketTot) {
    __shared__ unsigned tmp[256];
    int b = blockIdx.x, t = threadIdx.x;
    unsigned* row = histT + (size_t)b * NBLK_S;
    int i0 = t * 2, i1 = t * 2 + 1;
    unsigned v0 = (i0 < NBLK_S) ? row[i0] : 0u;
    unsigned v1 = (i1 < NBLK_S) ? row[i1] : 0u;
    unsigned s = v0 + v1;
    tmp[t] = s;
    __syncthreads();
    #pragma unroll
    for (int off = 1; off < 256; off <<= 1) {
        unsigned a = (t >= off) ? tmp[t - off] : 0u;
        __syncthreads();
        tmp[t] += a;
        __syncthreads();
    }
    unsigned base = tmp[t] - s;
    if (i0 < NBLK_S) row[i0] = base;
    if (i1 < NBLK_S) row[i1] = base + v0;
    if (t == 255) bucketTot[b] = tmp[255];
}

__global__ __launch_bounds__(256) void bucket_scan_b_kernel(const unsigned* __restrict__ bucketTot,
                                                            unsigned* __restrict__ bucketBase) {
    __shared__ unsigned tmp[256];
    int t = threadIdx.x;
    unsigned v = (t < NBUCK) ? bucketTot[t] : 0u;
    tmp[t] = v;
    __syncthreads();
    #pragma unroll
    for (int off = 1; off < 256; off <<= 1) {
        unsigned a = (t >= off) ? tmp[t - off] : 0u;
        __syncthreads();
        tmp[t] += a;
        __syncthreads();
    }
    if (t < NBUCK) bucketBase[t] = tmp[t] - v;
    if (t == NBUCK - 1) bucketBase[NBUCK] = tmp[t];
}

__global__ __launch_bounds__(256) void bucket_scatter_kernel(const int* __restrict__ ei,
                                                             const unsigned* __restrict__ histT,
                                                             const unsigned* __restrict__ bucketBase,
                                                             unsigned long long* __restrict__ ebuf) {
    __shared__ unsigned lcur[NBUCK];
    int t = threadIdx.x, j = blockIdx.x;
    for (int i = t; i < NBUCK; i += 256)
        lcur[i] = histT[(size_t)i * NBLK_S + j] + bucketBase[i];
    __syncthreads();
    int base = j * EPB;
    #pragma unroll
    for (int it = 0; it < EPB / 256; it++) {
        int e = base + it * 256 + t;
        if (e < N_EDGES) {
            unsigned src = (unsigned)ei[e];
            unsigned dst = (unsigned)ei[N_EDGES + e];
            unsigned pos = atomicAdd(&lcur[dst >> 8], 1u);
            ebuf[pos] = (unsigned long long)src | ((unsigned long long)dst << 32);
        }
    }
}

__global__ __launch_bounds__(256) void fine_fill_kernel(const unsigned long long* __restrict__ ebuf,
                                                        const unsigned* __restrict__ bucketBase,
                                                        unsigned* __restrict__ rowptr,
                                                        int* __restrict__ adj) {
    __shared__ unsigned ldeg[256], lcur[256], tmp[256];
    int b = blockIdx.x, t = threadIdx.x;
    unsigned sbase = bucketBase[b];
    int scnt = (int)(bucketBase[b + 1] - sbase);
    ldeg[t] = 0;
    __syncthreads();
    for (int k = t; k < scnt; k += 256) {
        unsigned dst = (unsigned)(ebuf[sbase + k] >> 32);
        atomicAdd(&ldeg[dst & 255], 1u);
    }
    __syncthreads();
    unsigned v = ldeg[t];
    tmp[t] = v;
    __syncthreads();
    for (int off = 1; off < 256; off <<= 1) {
        unsigned a = (t >= off) ? tmp[t - off] : 0u;
        __syncthreads();
        tmp[t] += a;
        __syncthreads();
    }
    unsigned exc = tmp[t] - v;
    lcur[t] = exc;
    int gnode = b * 256 + t;
    if (gnode < N_NODES) rowptr[gnode] = sbase + exc;
    if (b == NBUCK - 1 && t == 0) rowptr[N_NODES] = N_EDGES;
    __syncthreads();
    for (int k = t; k < scnt; k += 256) {
        unsigned long long p = ebuf[sbase + k];
        unsigned dst = (unsigned)(p >> 32);
        unsigned pos = atomicAdd(&lcur[dst & 255], 1u);
        adj[sbase + pos] = (int)(p & 0xffffffffu);
    }
}

// ---------------- x fp32 -> bf16 convert ----------------

__global__ __launch_bounds__(256) void convert_x_kernel(const float* __restrict__ x,
                                                        bf16_t* __restrict__ xb) {
    int i = blockIdx.x * 256 + threadIdx.x;
    if (i < N_NODES * N_FEAT / 4) {
        float4 v = reinterpret_cast<const float4*>(x)[i];
        short4 o;
        o.x = f2bfb(v.x); o.y = f2bfb(v.y); o.z = f2bfb(v.z); o.w = f2bfb(v.w);
        reinterpret_cast<short4*>(xb)[i] = o;
    }
}

// ---------------- Weight prep: fp32 W[K][256] -> bf16 Wt[256][K] ----------------

__global__ __launch_bounds__(256) void prep_weights_kernel(
    const float* __restrict__ c1_w0, const float* __restrict__ c1_w1,
    const float* __restrict__ cs_w0, const float* __restrict__ cs_w1,
    bf16_t* __restrict__ wt)
{
    __shared__ float T[32][33];
    int z = blockIdx.z;
    const float* src; int K; size_t off;
    if (z == 0)      { src = c1_w0; K = N_FEAT;  off = 0; }
    else if (z == 1) { src = c1_w1; K = HIDDEN;  off = 32768; }
    else {
        int i = (z - 2) >> 1;
        src = (((z - 2) & 1) ? cs_w1 : cs_w0) + (size_t)i * HIDDEN * HIDDEN;
        K = HIDDEN;
        off = 32768 + (size_t)(z - 1) * 65536;
    }
    int k0 = blockIdx.x * 32, n0 = blockIdx.y * 32;
    if (k0 >= K) return;
    int t = threadIdx.x;
    int r = t >> 3, c4 = (t & 7) * 4;
    float4 v = *reinterpret_cast<const float4*>(src + (size_t)(k0 + r) * HIDDEN + n0 + c4);
    T[r][c4 + 0] = v.x; T[r][c4 + 1] = v.y; T[r][c4 + 2] = v.z; T[r][c4 + 3] = v.w;
    __syncthreads();
    int n = t >> 3, kc = (t & 7) * 4;
    short4 o;
    o.x = f2bfb(T[kc + 0][n]); o.y = f2bfb(T[kc + 1][n]);
    o.z = f2bfb(T[kc + 2][n]); o.w = f2bfb(T[kc + 3][n]);
    *reinterpret_cast<short4*>((short*)wt + off + (size_t)(n0 + n) * K + k0 + kc) = o;
}

// ---------------- Aggregation layer 1: bf16 xb[N][128] -> bf16 out[N][128] ----------------

__global__ __launch_bounds__(256) void aggregate1_kernel(
    const bf16_t* __restrict__ xb, const int* __restrict__ adj,
    const unsigned* __restrict__ rowptr, const float* __restrict__ eps_arr,
    bf16_t* __restrict__ out)
{
    int w = threadIdx.x >> 6, lane = threadIdx.x & 63;
    int n = blockIdx.x * 4 + w;
    if (n >= N_NODES) return;
    int q = lane >> 4, l4 = lane & 15;
    unsigned beg = rowptr[n], end = rowptr[n + 1];
    const short* xs = (const short*)xb;
    float acc[8] = {};
    unsigned e = beg;
    for (; e + 8 <= end; e += 8) {
        int s0 = adj[e + q];
        int s1 = adj[e + 4 + q];
        bf16x8 v0 = *reinterpret_cast<const bf16x8*>(xs + (unsigned)s0 * N_FEAT + l4 * 8);
        bf16x8 v1 = *reinterpret_cast<const bf16x8*>(xs + (unsigned)s1 * N_FEAT + l4 * 8);
        #pragma unroll
        for (int j = 0; j < 8; j++) acc[j] += bfb2f(v0[j]) + bfb2f(v1[j]);
    }
    for (; e + 4 <= end; e += 4) {
        int s0 = adj[e + q];
        bf16x8 v0 = *reinterpret_cast<const bf16x8*>(xs + (unsigned)s0 * N_FEAT + l4 * 8);
        #pragma unroll
        for (int j = 0; j < 8; j++) acc[j] += bfb2f(v0[j]);
    }
    int rem = (int)(end - e);
    if (q < rem) {
        bf16x8 v0 = *reinterpret_cast<const bf16x8*>(xs + (unsigned)adj[e + q] * N_FEAT + l4 * 8);
        #pragma unroll
        for (int j = 0; j < 8; j++) acc[j] += bfb2f(v0[j]);
    }
    if (q == 0) {
        bf16x8 sv = *reinterpret_cast<const bf16x8*>(xs + (unsigned)n * N_FEAT + l4 * 8);
        float ep = 1.f + eps_arr[0];
        #pragma unroll
        for (int j = 0; j < 8; j++) acc[j] += ep * bfb2f(sv[j]);
    }
    #pragma unroll
    for (int j = 0; j < 8; j++) {
        acc[j] += __shfl_xor(acc[j], 16);
        acc[j] += __shfl_xor(acc[j], 32);
    }
    if (lane < 16) {
        bf16x8 o;
        #pragma unroll
        for (int j = 0; j < 8; j++) o[j] = f2bfb(acc[j]);
        *reinterpret_cast<bf16x8*>((short*)out + (unsigned)n * N_FEAT + l4 * 8) = o;
    }
}

// ---------------- Aggregation layers 2-4: bf16 [N][256] -> bf16 [N][256] ----------------

__global__ __launch_bounds__(256) void aggregate2_kernel(
    const bf16_t* __restrict__ x, const int* __restrict__ adj,
    const unsigned* __restrict__ rowptr, const float* __restrict__ eps_arr, int eps_idx,
    bf16_t* __restrict__ out)
{
    int w = threadIdx.x >> 6, lane = threadIdx.x & 63;
    int n = blockIdx.x * 4 + w;
    if (n >= N_NODES) return;
    int half = lane >> 5, l5 = lane & 31;
    unsigned beg = rowptr[n], end = rowptr[n + 1];
    const short* xs = (const short*)x;
    float acc[8] = {};
    unsigned e = beg;
    for (; e + 8 <= end; e += 8) {
        int s0 = adj[e + half];
        int s1 = adj[e + 2 + half];
        int s2 = adj[e + 4 + half];
        int s3 = adj[e + 6 + half];
        bf16x8 v0 = *reinterpret_cast<const bf16x8*>(xs + (unsigned)s0 * HIDDEN + l5 * 8);
        bf16x8 v1 = *reinterpret_cast<const bf16x8*>(xs + (unsigned)s1 * HIDDEN + l5 * 8);
        bf16x8 v2 = *reinterpret_cast<const bf16x8*>(xs + (unsigned)s2 * HIDDEN + l5 * 8);
        bf16x8 v3 = *reinterpret_cast<const bf16x8*>(xs + (unsigned)s3 * HIDDEN + l5 * 8);
        #pragma unroll
        for (int j = 0; j < 8; j++)
            acc[j] += (bfb2f(v0[j]) + bfb2f(v1[j])) + (bfb2f(v2[j]) + bfb2f(v3[j]));
    }
    for (; e + 2 <= end; e += 2) {
        int s0 = adj[e + half];
        bf16x8 v0 = *reinterpret_cast<const bf16x8*>(xs + (unsigned)s0 * HIDDEN + l5 * 8);
        #pragma unroll
        for (int j = 0; j < 8; j++) acc[j] += bfb2f(v0[j]);
    }
    if (e < end && half == 0) {
        bf16x8 v0 = *reinterpret_cast<const bf16x8*>(xs + (unsigned)adj[e] * HIDDEN + l5 * 8);
        #pragma unroll
        for (int j = 0; j < 8; j++) acc[j] += bfb2f(v0[j]);
    }
    if (half == 0) {
        bf16x8 sv = *reinterpret_cast<const bf16x8*>(xs + (unsigned)n * HIDDEN + l5 * 8);
        float ep = 1.f + eps_arr[eps_idx];
        #pragma unroll
        for (int j = 0; j < 8; j++) acc[j] += ep * bfb2f(sv[j]);
    }
    #pragma unroll
    for (int j = 0; j < 8; j++) acc[j] += __shfl_xor(acc[j], 32);
    if (half == 0) {
        bf16x8 o;
        #pragma unroll
        for (int j = 0; j < 8; j++) o[j] = f2bfb(acc[j]);
        *reinterpret_cast<bf16x8*>((short*)out + (unsigned)n * HIDDEN + l5 * 8) = o;
    }
}

// ---------------- bf16 MFMA GEMM with async global_load_lds staging ----------------
// 128x128 tile, 512 threads, 8 waves (2x4), wave tile 64x32, BK=64.
// LDS: As[128][64] + Bs[128][64] linear (32 KB), Cs[128][136] epilogue overlay (34.8 KB).
// Staging: width-16 global_load_lds, linear LDS dest, inverse-XOR-swizzled global src;
// fragment reads apply the same swizzle (col ^ ((row&7)<<3) on short index) -> 2-way free.
// A buffer MUST be row-padded to >= gridDim.x*128 rows (MPAD) — staging is unguarded.

__global__ __launch_bounds__(512) void gemm_bf16_kernel(
    const bf16_t* __restrict__ A, const bf16_t* __restrict__ Wt,
    const float* __restrict__ bias, bf16_t* __restrict__ C,
    int M, int K,
    const float* __restrict__ bn_g, const float* __restrict__ bn_b,
    const float* __restrict__ bn_m, const float* __restrict__ bn_v, int do_bn)
{
    __shared__ short lds[17408];                    // 34.8 KB
    short* As = lds;                                // [128][64] linear
    short* Bs = lds + 8192;                         // [128][64] linear
    short (*Cs)[136] = reinterpret_cast<short(*)[136]>(lds);   // epilogue overlay

    int tid = threadIdx.x, lane = tid & 63, wave = tid >> 6;
    int wr = wave >> 2, wc = wave & 3;              // 2 x 4 wave grid, wave tile 64x32
    int row0 = blockIdx.x * 128, col0 = blockIdx.y * 128;
    int fr = lane & 15, fkq = lane >> 4;            // fragment row / k-quad

    const short* Ab = (const short*)A;
    const short* Wb = (const short*)Wt;

    f32x4 acc[4][2] = {};

    for (int k0 = 0; k0 < K; k0 += 64) {
        #pragma unroll
        for (int rnd = 0; rnd < 2; rnd++) {
            int p = rnd * 512 + tid;                // 1024 chunks of 16B per tile
            int r = p >> 3, cch = p & 7;
            int scol = (cch * 8) ^ ((r & 7) << 3);  // inverse swizzle on source
            async_copy16(Ab + (size_t)(row0 + r) * K + k0 + scol, &As[p * 8]);
            async_copy16(Wb + (size_t)(col0 + r) * K + k0 + scol, &Bs[p * 8]);
        }
        __syncthreads();                            // drains vmcnt (compiler-inserted)

        #pragma unroll
        for (int ks = 0; ks < 2; ks++) {
            bf16x8 a[4], b[2];
            #pragma unroll
            for (int m = 0; m < 4; m++) {
                int r = wr * 64 + m * 16 + fr;
                a[m] = *reinterpret_cast<const bf16x8*>(
                    &As[r * 64 + ((ks * 32 + fkq * 8) ^ ((r & 7) << 3))]);
            }
            #pragma unroll
            for (int n = 0; n < 2; n++) {
                int rb = wc * 32 + n * 16 + fr;
                b[n] = *reinterpret_cast<const bf16x8*>(
                    &Bs[rb * 64 + ((ks * 32 + fkq * 8) ^ ((rb & 7) << 3))]);
            }
            #pragma unroll
            for (int m = 0; m < 4; m++)
                #pragma unroll
                for (int n = 0; n < 2; n++)
                    acc[m][n] = __builtin_amdgcn_mfma_f32_16x16x32_bf16(a[m], b[n], acc[m][n], 0, 0, 0);
        }
        __syncthreads();
    }

    // epilogue: bias + relu (+BN) -> bf16 -> Cs overlay -> coalesced stores
    #pragma unroll
    for (int m = 0; m < 4; m++) {
        #pragma unroll
        for (int n = 0; n < 2; n++) {
            int rl = wr * 64 + m * 16 + (lane >> 4) * 4;
            int cl = wc * 32 + n * 16 + (lane & 15);
            int c = col0 + cl;
            float bi = bias[c];
            #pragma unroll
            for (int r = 0; r < 4; r++) {
                float v = acc[m][n][r] + bi;
                v = fmaxf(v, 0.f);
                if (do_bn) v = (v - bn_m[c]) * rsqrtf(bn_v[c] + 1e-5f) * bn_g[c] + bn_b[c];
                Cs[rl + r][cl] = f2bfb(v);
            }
        }
    }
    __syncthreads();
    int lr = tid >> 2, c16 = tid & 3;
    int r = row0 + lr;
    if (r < M) {
        short* Cb = (short*)C;
        #pragma unroll
        for (int cc = 0; cc < 4; cc++) {
            int ch = c16 + cc * 4;
            bf16x8 cv = *reinterpret_cast<const bf16x8*>(&Cs[lr][ch * 8]);
            *reinterpret_cast<bf16x8*>(Cb + (size_t)r * HIDDEN + col0 + ch * 8) = cv;
        }
    }
}

// ---------------- Pool ----------------

__global__ __launch_bounds__(256) void pool_kernel(const bf16_t* __restrict__ h,
                                                   const int* __restrict__ batch,
                                                   float* __restrict__ pooled) {
    __shared__ int sbs[2];
    __shared__ float red[4][HIDDEN];
    int g = blockIdx.x;
    if (threadIdx.x == 0) {
        int lo = 0, hi = N_NODES;
        while (lo < hi) { int mid = (lo + hi) >> 1; if (batch[mid] < g) lo = mid + 1; else hi = mid; }
        sbs[0] = lo;
        hi = N_NODES;
        while (lo < hi) { int mid = (lo + hi) >> 1; if (batch[mid] < g + 1) lo = mid + 1; else hi = mid; }
        sbs[1] = lo;
    }
    __syncthreads();
    int sbeg = sbs[0], send = sbs[1];
    int w = threadIdx.x >> 6, lane = threadIdx.x & 63;
    int half = lane >> 5, l5 = lane & 31;
    const short* hb = (const short*)h;
    float acc[8] = {};
    for (int n = sbeg + w * 2 + half; n < send; n += 8) {
        bf16x8 v = *reinterpret_cast<const bf16x8*>(hb + (size_t)n * HIDDEN + l5 * 8);
        #pragma unroll
        for (int j = 0; j < 8; j++) acc[j] += bfb2f(v[j]);
    }
    #pragma unroll
    for (int j = 0; j < 8; j++) acc[j] += __shfl_xor(acc[j], 32);
    if (half == 0) {
        #pragma unroll
        for (int j = 0; j < 8; j++) red[w][l5 * 8 + j] = acc[j];
    }
    __syncthreads();
    int t = threadIdx.x;
    float s = red[0][t] + red[1][t] + red[2][t] + red[3][t];
    float cnt = (float)(send - sbeg);
    pooled[g * HIDDEN + t] = s / fmaxf(cnt, 1.f);
}

// ---------------- Head ----------------

__global__ void head_kernel(const float* __restrict__ pooled,
                            const float* __restrict__ w1, const float* __restrict__ b1,
                            const float* __restrict__ w2, const float* __restrict__ b2,
                            float* __restrict__ out) {
    int g = blockIdx.x, t = threadIdx.x;
    __shared__ float p[HIDDEN];
    __shared__ float h1[HIDDEN];
    __shared__ float lg[N_CLASSES];
    p[t] = pooled[g * HIDDEN + t];
    __syncthreads();
    float acc = b1[t];
    for (int k = 0; k < HIDDEN; k++) acc += p[k] * w1[k * HIDDEN + t];
    h1[t] = fmaxf(acc, 0.f);
    __syncthreads();
    if (t < N_CLASSES) {
        float a = b2[t];
        for (int k = 0; k < HIDDEN; k++) a += h1[k] * w2[k * N_CLASSES + t];
        lg[t] = a;
    }
    __syncthreads();
    if (t == 0) {
        float mx = lg[0];
        for (int j = 1; j < N_CLASSES; j++) mx = fmaxf(mx, lg[j]);
        float se = 0.f;
        for (int j = 0; j < N_CLASSES; j++) se += expf(lg[j] - mx);
        float lse = mx + logf(se);
        for (int j = 0; j < N_CLASSES; j++) out[g * N_CLASSES + j] = lg[j] - lse;
    }
}

// ---------------- Launch ----------------

extern "C" void kernel_launch(void* const* d_in, const int* in_sizes, int n_in,
                              void* d_out, int out_size, void* d_ws, size_t ws_size,
                              hipStream_t stream) {
    const float* x       = (const float*)d_in[0];
    const int*   ei      = (const int*)d_in[1];     // int32 on device (harness contract)
    const int*   batch   = (const int*)d_in[2];
    const float* c1_w0   = (const float*)d_in[3];
    const float* c1_b0   = (const float*)d_in[4];
    const float* c1_w1   = (const float*)d_in[5];
    const float* c1_b1   = (const float*)d_in[6];
    const float* c1_g    = (const float*)d_in[7];
    const float* c1_be   = (const float*)d_in[8];
    const float* c1_m    = (const float*)d_in[9];
    const float* c1_v    = (const float*)d_in[10];
    const float* cs_w0   = (const float*)d_in[11];
    const float* cs_b0   = (const float*)d_in[12];
    const float* cs_w1   = (const float*)d_in[13];
    const float* cs_b1   = (const float*)d_in[14];
    const float* cs_g    = (const float*)d_in[15];
    const float* cs_be   = (const float*)d_in[16];
    const float* cs_m    = (const float*)d_in[17];
    const float* cs_v    = (const float*)d_in[18];
    const float* eps     = (const float*)d_in[19];
    const float* lin1_w  = (const float*)d_in[20];
    const float* lin1_b  = (const float*)d_in[21];
    const float* lin2_w  = (const float*)d_in[22];
    const float* lin2_b  = (const float*)d_in[23];

    char* ws = (char*)d_ws;
    size_t off = 0;
    auto alloc = [&](size_t bytes) -> void* {
        void* p = ws + off;
        off += (bytes + 255) & ~(size_t)255;
        return p;
    };

    unsigned* histT      = (unsigned*)alloc((size_t)NBUCK * NBLK_S * 4);
    unsigned* bucketTot  = (unsigned*)alloc(NBUCK * 4);
    unsigned* bucketBase = (unsigned*)alloc((NBUCK + 1) * 4);
    unsigned long long* ebuf = (unsigned long long*)alloc((size_t)N_EDGES * 8);
    unsigned* rowptr     = (unsigned*)alloc((N_NODES + 1) * 4);
    int*      adj        = (int*)alloc(N_EDGES * 4);
    bf16_t*   Wt         = (bf16_t*)alloc((size_t)(32768 + 7 * 65536) * 2);
    bf16_t*   xb         = (bf16_t*)alloc((size_t)N_NODES * N_FEAT * 2);
    bf16_t*   B1         = (bf16_t*)alloc((size_t)MPAD * HIDDEN * 2);   // padded for staging
    bf16_t*   B2         = (bf16_t*)alloc((size_t)MPAD * HIDDEN * 2);
    bf16_t*   B3         = (bf16_t*)alloc((size_t)MPAD * HIDDEN * 2);
    float*    pooled     = (float*)alloc(N_GRAPHS * HIDDEN * 4);

    bf16_t* wt_10 = Wt;                       // c1_w0^T  [256][128]
    bf16_t* wt_11 = Wt + 32768;               // c1_w1^T  [256][256]
    auto wt_c0 = [&](int i) { return Wt + 32768 + (size_t)(1 + 2 * i) * 65536; };
    auto wt_c1 = [&](int i) { return Wt + 32768 + (size_t)(2 + 2 * i) * 65536; };

    // CSR build (5 dispatches, all parallel)
    bucket_hist_kernel<<<NBLK_S, 256, 0, stream>>>(ei, histT);
    bucket_scan_a_kernel<<<NBUCK, 256, 0, stream>>>(histT, bucketTot);
    bucket_scan_b_kernel<<<1, 256, 0, stream>>>(bucketTot, bucketBase);
    bucket_scatter_kernel<<<NBLK_S, 256, 0, stream>>>(ei, histT, bucketBase, ebuf);
    fine_fill_kernel<<<NBUCK, 256, 0, stream>>>(ebuf, bucketBase, rowptr, adj);

    convert_x_kernel<<<(N_NODES * N_FEAT / 4 + 255) / 256, 256, 0, stream>>>(x, xb);
    prep_weights_kernel<<<dim3(8, 8, 8), 256, 0, stream>>>(c1_w0, c1_w1, cs_w0, cs_w1, Wt);

    dim3 ggrid((N_NODES + 127) / 128, 2);    // 391 x 2
    int ab = (N_NODES + 3) / 4;

    // Layer 1 (F=128)
    aggregate1_kernel<<<ab, 256, 0, stream>>>(xb, adj, rowptr, eps, B1);
    gemm_bf16_kernel<<<ggrid, 512, 0, stream>>>(B1, wt_10, c1_b0, B2, N_NODES, N_FEAT,
                                                nullptr, nullptr, nullptr, nullptr, 0);
    gemm_bf16_kernel<<<ggrid, 512, 0, stream>>>(B2, wt_11, c1_b1, B3, N_NODES, HIDDEN,
                                                c1_g, c1_be, c1_m, c1_v, 1);

    // Layers 2..4 (F=256)
    for (int i = 0; i < 3; i++) {
        aggregate2_kernel<<<ab, 256, 0, stream>>>(B3, adj, rowptr, eps, i + 1, B1);
        gemm_bf16_kernel<<<ggrid, 512, 0, stream>>>(B1, wt_c0(i), cs_b0 + i * HIDDEN, B2,
                                                    N_NODES, HIDDEN,
                                                    nullptr, nullptr, nullptr, nullptr, 0);
        gemm_bf16_kernel<<<ggrid, 512, 0, stream>>>(B2, wt_c1(i), cs_b1 + i * HIDDEN, B3,
                                                    N_NODES, HIDDEN,
                                                    cs_g + i * HIDDEN, cs_be + i * HIDDEN,
                                                    cs_m + i * HIDDEN, cs_v + i * HIDDEN, 1);
    }

    pool_kernel<<<N_GRAPHS, 256, 0, stream>>>(B3, batch, pooled);
    head_kernel<<<N_GRAPHS, HIDDEN, 0, stream>>>(pooled, lin1_w, lin1_b, lin2_w, lin2_b, (float*)d_out);
}